// Round 9
// baseline (262.596 us; speedup 1.0000x reference)
//
#include <hip/hip_runtime.h>
#include <hip/hip_bf16.h>

#define IN_F   1024
#define OUT_F  1024
#define TOKENS 8192
#define KTOT   9216
#define KHALF  4608
#define NTILE  72          // KHALF / 64

typedef __attribute__((ext_vector_type(8))) short  bf16x8;
typedef __attribute__((ext_vector_type(4))) float  f32x4;

template<int M> struct ModeT { static constexpr int value = M; };

__device__ __forceinline__ unsigned int f2bf(float f) {
    union { float f; unsigned int u; } v; v.f = f;
    unsigned int r = v.u + 0x7fffu + ((v.u >> 16) & 1u);
    return r >> 16;
}

__device__ __forceinline__ void prep_a_body(int idx, const float* __restrict__ x,
                                            const float* __restrict__ grid,
                                            unsigned short* __restrict__ A)
{
    int t = idx >> 10;
    int i = idx & 1023;
    float xv = x[idx];
    float sil = xv / (1.0f + __expf(-xv));
    A[(size_t)t * KTOT + i] = (unsigned short)f2bf(sil);

    const float invd = 1.0f / (2.0f / 7.0f + 1e-5f);
    unsigned int h[8];
    #pragma unroll
    for (int g = 0; g < 8; ++g) {
        float d = (xv - grid[g]) * invd;
        h[g] = f2bf(__expf(-d * d));
    }
    uint4 pk;
    pk.x = h[0] | (h[1] << 16);
    pk.y = h[2] | (h[3] << 16);
    pk.z = h[4] | (h[5] << 16);
    pk.w = h[6] | (h[7] << 16);
    *reinterpret_cast<uint4*>(&A[(size_t)t * KTOT + IN_F + (size_t)i * 8]) = pk;
}

__device__ __forceinline__ void prep_b_body(int idx, const float* __restrict__ W,
                                            const float* __restrict__ spl,
                                            unsigned short* __restrict__ B)
{
    int o  = idx / (KTOT / 8);
    int c8 = idx - o * (KTOT / 8);
    const float* src = (c8 < IN_F / 8)
        ? (W   + (size_t)o * IN_F     + (size_t)c8 * 8)
        : (spl + (size_t)o * IN_F * 8 + (size_t)(c8 - IN_F / 8) * 8);
    const float4* s4 = reinterpret_cast<const float4*>(src);
    float4 lo = s4[0], hi = s4[1];
    uint4 pk;
    pk.x = f2bf(lo.x) | (f2bf(lo.y) << 16);
    pk.y = f2bf(lo.z) | (f2bf(lo.w) << 16);
    pk.z = f2bf(hi.x) | (f2bf(hi.y) << 16);
    pk.w = f2bf(hi.z) | (f2bf(hi.w) << 16);
    *reinterpret_cast<uint4*>(&B[(size_t)o * KTOT + (size_t)c8 * 8]) = pk;
}

// Fused A+B prep: blocks [0, 32768) build A (silu + basis), rest repack B.
__global__ __launch_bounds__(256)
void prep_fused(const float* __restrict__ x, const float* __restrict__ grid,
                const float* __restrict__ W, const float* __restrict__ spl,
                unsigned short* __restrict__ A, unsigned short* __restrict__ B)
{
    int b = blockIdx.x;
    if (b < (TOKENS * IN_F) / 256)
        prep_a_body(b * 256 + threadIdx.x, x, grid, A);
    else
        prep_b_body((b - (TOKENS * IN_F) / 256) * 256 + threadIdx.x, W, spl, B);
}

__global__ __launch_bounds__(256)
void prep_a_kernel(const float* __restrict__ x, const float* __restrict__ grid,
                   unsigned short* __restrict__ A)
{
    prep_a_body(blockIdx.x * blockDim.x + threadIdx.x, x, grid, A);
}

__global__ __launch_bounds__(256)
void prep_b_kernel(const float* __restrict__ W, const float* __restrict__ spl,
                   unsigned short* __restrict__ B)
{
    prep_b_body(blockIdx.x * blockDim.x + threadIdx.x, W, spl, B);
}

// ---------------------------------------------------------------------------
// 256x256 tile, BK=64, 8 waves (2M x 4N), split-K=2.
// R9: B-operand LOADED GLOBAL->REGISTER (L2-resident per XCD: bid&7 -> (sk,bn)
// so each XCD's 2.36 MB B-slice lives in its L2). LDS holds A only (64 KB
// dbuf): per-CU LDS traffic/tile drops 192->128 KB and B-reads move to the
// VMEM pipe, concurrent with LDS. B prefetch via WAR register reuse with
// quadrant order q00(L) q10(L) q01(H) q11(H):
//   bfH(u) loaded at tile start  (covered by q00+q10 ~620 cy)
//   bfL(u+1) loaded after q10    (covered by q01+q11 ~620 cy)
// A staging: 4 x global_load_lds per thread; tile-end VMC0+SBAR (R6-proven).
//   A row(mi) = wr*64 + (mi&3)*16 + (mi>>2)*128
//   B col(ni) = wc*32 + (ni&1)*16 + (ni>>1)*128
// ---------------------------------------------------------------------------
#define GLOAD(src, dst) __builtin_amdgcn_global_load_lds( \
    (const __attribute__((address_space(1))) void*)(src),  \
    (__attribute__((address_space(3))) void*)(dst), 16, 0, 0)
#define SBAR()  __builtin_amdgcn_s_barrier()
#define SCH0()  __builtin_amdgcn_sched_barrier(0)
#define VMC0()  asm volatile("s_waitcnt vmcnt(0)" ::: "memory")

__global__ __launch_bounds__(512, 2)
void gemm_kan2(const unsigned short* __restrict__ A,
               const unsigned short* __restrict__ B,
               float* __restrict__ P, int rows)
{
    __shared__ char lds[65536];   // A dbuf only: 2 x 32 KB

    const int bid  = blockIdx.x;
    const int sk   = bid & 1;            // XCD = bid&7 owns one (bn,sk) pair:
    const int bn   = (bid >> 1) & 3;     // its 2.36 MB B-panel stays in its L2
    const int bm   = bid >> 3;
    const int tid  = threadIdx.x;
    const int wave = tid >> 6, lane = tid & 63;
    const int wr   = wave >> 2, wc = wave & 3;
    const int fr   = lane & 15, kg = lane >> 4;
    const int sw   = fr & 7;
    const int koff[2] = { (kg ^ sw) * 16, ((4 | kg) ^ sw) * 16 };
    const int k0 = sk * KHALF;

    // A staging: thread covers row (tid>>3), 16B chunk (tid&7), inverse-swizzled k
    const int trow = tid >> 3;
    const int ksrc = ((tid & 7) ^ (trow & 7)) * 8;
    const unsigned short* gA = A + (size_t)(bm * 256 + trow) * KTOT + k0 + ksrc;
    const size_t R64 = (size_t)64 * KTOT;

    // B per-lane fragment pointers (global, unswizzled). Lane (fr,kg) of one
    // load instr: 16 rows x 64B contiguous -> coalesced L2 reads.
    const unsigned short* gB00 = B + (size_t)(bn * 256 + wc * 32 + fr) * KTOT + k0 + kg * 8;
    const unsigned short* gB01 = gB00 + (size_t)16  * KTOT;
    const unsigned short* gB10 = gB00 + (size_t)128 * KTOT;
    const unsigned short* gB11 = gB00 + (size_t)144 * KTOT;

    f32x4 acc[8][4];
    const f32x4 zero = {0.f, 0.f, 0.f, 0.f};
    #pragma unroll
    for (int m = 0; m < 8; ++m)
        #pragma unroll
        for (int n = 0; n < 4; ++n) acc[m][n] = zero;

    bf16x8 afLo[4][2], afHi[4][2], bfL[2][2], bfH[2][2];

    // prologue: stage A(0) -> buf0; load bfL(0)
    {
        char* dA = lds + tid * 16;
        GLOAD(gA,           dA);           GLOAD(gA + R64,     dA + 8192);
        GLOAD(gA + 2 * R64, dA + 16384);   GLOAD(gA + 3 * R64, dA + 24576);
        gA += 64;
        #pragma unroll
        for (int ks = 0; ks < 2; ++ks) {
            bfL[0][ks] = *(const bf16x8*)(gB00 + ks * 32);
            bfL[1][ks] = *(const bf16x8*)(gB01 + ks * 32);
        }
    }
    VMC0(); SBAR(); SCH0();

    const int aOff = (wr * 64 + fr) * 128;   // + (mi&3)*2048; +16384 for hi half

    int u = 0;

    // MODE: 0 = steady (stages A(u+1), prefetches bfL(u+1)), 1 = last tile
    auto tile = [&](auto mC) {
        constexpr int MODE = decltype(mC)::value;
        char* bufA = lds + (u & 1) * 32768;

        // ---- A-frag reads: af-lo + af-hi (16 x ds_read_b128) ----
        #pragma unroll
        for (int mi = 0; mi < 4; ++mi)
            #pragma unroll
            for (int ks = 0; ks < 2; ++ks) {
                afLo[mi][ks] = *(const bf16x8*)(bufA + aOff + mi * 2048 + koff[ks]);
                afHi[mi][ks] = *(const bf16x8*)(bufA + aOff + 16384 + mi * 2048 + koff[ks]);
            }

        // ---- load bfH(u) from global (4 x 16B; covered by q00+q10) ----
        #pragma unroll
        for (int ks = 0; ks < 2; ++ks) {
            bfH[0][ks] = *(const bf16x8*)(gB10 + ks * 32);
            bfH[1][ks] = *(const bf16x8*)(gB11 + ks * 32);
        }

        // ---- stage A(u+1) ----
        if constexpr (MODE == 0) {
            char* dA = lds + ((u & 1) ^ 1) * 32768 + tid * 16;
            GLOAD(gA,           dA);           GLOAD(gA + R64,     dA + 8192);
            GLOAD(gA + 2 * R64, dA + 16384);   GLOAD(gA + 3 * R64, dA + 24576);
            gA += 64;
        }
        SCH0();

        // ---- q00: af-lo x bfL ----
        __builtin_amdgcn_s_setprio(1);
        #pragma unroll
        for (int mi = 0; mi < 4; ++mi)
            #pragma unroll
            for (int ni = 0; ni < 2; ++ni)
                #pragma unroll
                for (int ks = 0; ks < 2; ++ks)
                    acc[mi][ni] = __builtin_amdgcn_mfma_f32_16x16x32_bf16(
                        afLo[mi][ks], bfL[ni][ks], acc[mi][ni], 0, 0, 0);
        __builtin_amdgcn_s_setprio(0);

        // ---- q10: af-hi x bfL ----
        __builtin_amdgcn_s_setprio(1);
        #pragma unroll
        for (int mi = 0; mi < 4; ++mi)
            #pragma unroll
            for (int ni = 0; ni < 2; ++ni)
                #pragma unroll
                for (int ks = 0; ks < 2; ++ks)
                    acc[4 + mi][ni] = __builtin_amdgcn_mfma_f32_16x16x32_bf16(
                        afHi[mi][ks], bfL[ni][ks], acc[4 + mi][ni], 0, 0, 0);
        __builtin_amdgcn_s_setprio(0);

        // ---- prefetch bfL(u+1) (WAR reg reuse; covered by q01+q11) ----
        if constexpr (MODE == 0) {
            #pragma unroll
            for (int ks = 0; ks < 2; ++ks) {
                bfL[0][ks] = *(const bf16x8*)(gB00 + 64 + ks * 32);
                bfL[1][ks] = *(const bf16x8*)(gB01 + 64 + ks * 32);
            }
        }

        // ---- q01: af-lo x bfH ----
        __builtin_amdgcn_s_setprio(1);
        #pragma unroll
        for (int mi = 0; mi < 4; ++mi)
            #pragma unroll
            for (int ni = 0; ni < 2; ++ni)
                #pragma unroll
                for (int ks = 0; ks < 2; ++ks)
                    acc[mi][2 + ni] = __builtin_amdgcn_mfma_f32_16x16x32_bf16(
                        afLo[mi][ks], bfH[ni][ks], acc[mi][2 + ni], 0, 0, 0);
        __builtin_amdgcn_s_setprio(0);

        // ---- q11: af-hi x bfH ----
        __builtin_amdgcn_s_setprio(1);
        #pragma unroll
        for (int mi = 0; mi < 4; ++mi)
            #pragma unroll
            for (int ni = 0; ni < 2; ++ni)
                #pragma unroll
                for (int ks = 0; ks < 2; ++ks)
                    acc[4 + mi][2 + ni] = __builtin_amdgcn_mfma_f32_16x16x32_bf16(
                        afHi[mi][ks], bfH[ni][ks], acc[4 + mi][2 + ni], 0, 0, 0);
        __builtin_amdgcn_s_setprio(0);

        SCH0();
        if constexpr (MODE == 0) {
            VMC0();          // A(u+1) resident; bfL(u+1)/bfH issued >=620cy ago
            SBAR(); SCH0();  // all waves done reading buf(u)
            gB00 += 64; gB01 += 64; gB10 += 64; gB11 += 64;
        }
    };

    for (u = 0; u < NTILE - 1; ++u) tile(ModeT<0>{});
    tile(ModeT<1>{});

    // epilogue: write f32 partials (interleaved-quadrant mapping)
    float* Pp = P + (size_t)sk * rows * OUT_F;
    const size_t orow0 = (size_t)bm * 256 + (size_t)wr * 64;
    const int    ocol0 = bn * 256 + wc * 32;
    #pragma unroll
    for (int n = 0; n < 4; ++n) {
        const int col = ocol0 + (n & 1) * 16 + (n >> 1) * 128 + fr;
        #pragma unroll
        for (int m = 0; m < 8; ++m) {
            const size_t r0 = orow0 + (m & 3) * 16 + (m >> 2) * 128 + kg * 4;
            #pragma unroll
            for (int j2 = 0; j2 < 4; ++j2)
                Pp[(r0 + j2) * OUT_F + col] = acc[m][n][j2];
        }
    }
}

// out = P0 + P1 + bias
__global__ __launch_bounds__(256)
void reduce_kan(const float* __restrict__ P, const float* __restrict__ bias,
                float* __restrict__ out, int n4, int skStride4)
{
    const float4* p0 = (const float4*)P;
    const float4* p1 = p0 + skStride4;
    const float4* bv = (const float4*)bias;
    float4* o = (float4*)out;
    for (int i = blockIdx.x * blockDim.x + threadIdx.x; i < n4;
         i += gridDim.x * blockDim.x) {
        float4 a = p0[i], b = p1[i], c = bv[i & 255];
        float4 r;
        r.x = a.x + b.x + c.x;  r.y = a.y + b.y + c.y;
        r.z = a.z + b.z + c.z;  r.w = a.w + b.w + c.w;
        o[i] = r;
    }
}

extern "C" void kernel_launch(void* const* d_in, const int* in_sizes, int n_in,
                              void* d_out, int out_size, void* d_ws, size_t ws_size,
                              hipStream_t stream)
{
    const float* x    = (const float*)d_in[0];
    const float* W    = (const float*)d_in[1];
    const float* bias = (const float*)d_in[2];
    const float* spl  = (const float*)d_in[3];
    const float* grid = (const float*)d_in[4];
    float* out = (float*)d_out;

    unsigned short* Bw = (unsigned short*)d_ws;               // 18.9 MB
    unsigned short* Aw = Bw + (size_t)OUT_F * KTOT;

    // per-row ws: A bf16 (18432 B) + 2x f32 partial (8192 B)
    const size_t bBytes = (size_t)OUT_F * KTOT * 2;
    size_t avail = ws_size > bBytes ? ws_size - bBytes : 0;
    long maxRows = (long)(avail / 26624);
    int chunk = (maxRows >= TOKENS) ? TOKENS : (int)((maxRows / 256) * 256);
    if (chunk < 256) chunk = 256;
    float* Pp = (float*)(Aw + (size_t)chunk * KTOT);

    if (chunk == TOKENS) {
        // fused prep (A + B in one BW-bound sweep), then one GEMM + reduce
        prep_fused<<<(TOKENS * IN_F) / 256 + (OUT_F * (KTOT / 8)) / 256,
                     256, 0, stream>>>(x, grid, W, spl, Aw, Bw);
        gemm_kan2<<<(TOKENS >> 8) * 8, 512, 0, stream>>>(Aw, Bw, Pp, TOKENS);
        int n4 = TOKENS * 256;
        reduce_kan<<<2048, 256, 0, stream>>>(Pp, bias, out, n4, n4);
    } else {
        prep_b_kernel<<<(OUT_F * (KTOT / 8)) / 256, 256, 0, stream>>>(W, spl, Bw);
        for (int t0 = 0; t0 < TOKENS; t0 += chunk) {
            int rows = (TOKENS - t0 < chunk) ? (TOKENS - t0) : chunk;
            prep_a_kernel<<<(rows * IN_F) / 256, 256, 0, stream>>>(
                x + (size_t)t0 * IN_F, grid, Aw);
            gemm_kan2<<<(rows >> 8) * 8, 512, 0, stream>>>(Aw, Bw, Pp, rows);
            int n4 = rows * 256;
            int rblocks = (n4 + 255) / 256; if (rblocks > 2048) rblocks = 2048;
            reduce_kan<<<rblocks, 256, 0, stream>>>(
                Pp, bias, out + (size_t)t0 * OUT_F, n4, n4);
        }
    }
}

// Round 10
// 193.353 us; speedup vs baseline: 1.3581x; 1.3581x over previous
//
#include <hip/hip_runtime.h>
#include <hip/hip_bf16.h>

#define IN_F   1024
#define OUT_F  1024
#define TOKENS 8192
#define KTOT   9216
#define KHALF  4608
#define NTILE  72          // KHALF / 64

typedef __attribute__((ext_vector_type(8))) short  bf16x8;
typedef __attribute__((ext_vector_type(4))) float  f32x4;

template<int M> struct ModeT { static constexpr int value = M; };

__device__ __forceinline__ unsigned int f2bf(float f) {
    union { float f; unsigned int u; } v; v.f = f;
    unsigned int r = v.u + 0x7fffu + ((v.u >> 16) & 1u);
    return r >> 16;
}

__device__ __forceinline__ void prep_a_body(int idx, const float* __restrict__ x,
                                            const float* __restrict__ grid,
                                            unsigned short* __restrict__ A)
{
    int t = idx >> 10;
    int i = idx & 1023;
    float xv = x[idx];
    float sil = xv / (1.0f + __expf(-xv));
    A[(size_t)t * KTOT + i] = (unsigned short)f2bf(sil);

    const float invd = 1.0f / (2.0f / 7.0f + 1e-5f);
    unsigned int h[8];
    #pragma unroll
    for (int g = 0; g < 8; ++g) {
        float d = (xv - grid[g]) * invd;
        h[g] = f2bf(__expf(-d * d));
    }
    uint4 pk;
    pk.x = h[0] | (h[1] << 16);
    pk.y = h[2] | (h[3] << 16);
    pk.z = h[4] | (h[5] << 16);
    pk.w = h[6] | (h[7] << 16);
    *reinterpret_cast<uint4*>(&A[(size_t)t * KTOT + IN_F + (size_t)i * 8]) = pk;
}

__device__ __forceinline__ void prep_b_body(int idx, const float* __restrict__ W,
                                            const float* __restrict__ spl,
                                            unsigned short* __restrict__ B)
{
    int o  = idx / (KTOT / 8);
    int c8 = idx - o * (KTOT / 8);
    const float* src = (c8 < IN_F / 8)
        ? (W   + (size_t)o * IN_F     + (size_t)c8 * 8)
        : (spl + (size_t)o * IN_F * 8 + (size_t)(c8 - IN_F / 8) * 8);
    const float4* s4 = reinterpret_cast<const float4*>(src);
    float4 lo = s4[0], hi = s4[1];
    uint4 pk;
    pk.x = f2bf(lo.x) | (f2bf(lo.y) << 16);
    pk.y = f2bf(lo.z) | (f2bf(lo.w) << 16);
    pk.z = f2bf(hi.x) | (f2bf(hi.y) << 16);
    pk.w = f2bf(hi.z) | (f2bf(hi.w) << 16);
    *reinterpret_cast<uint4*>(&B[(size_t)o * KTOT + (size_t)c8 * 8]) = pk;
}

// Fused A+B prep: blocks [0, 32768) build A (silu + basis), rest repack B.
__global__ __launch_bounds__(256)
void prep_fused(const float* __restrict__ x, const float* __restrict__ grid,
                const float* __restrict__ W, const float* __restrict__ spl,
                unsigned short* __restrict__ A, unsigned short* __restrict__ B)
{
    int b = blockIdx.x;
    if (b < (TOKENS * IN_F) / 256)
        prep_a_body(b * 256 + threadIdx.x, x, grid, A);
    else
        prep_b_body((b - (TOKENS * IN_F) / 256) * 256 + threadIdx.x, W, spl, B);
}

__global__ __launch_bounds__(256)
void prep_a_kernel(const float* __restrict__ x, const float* __restrict__ grid,
                   unsigned short* __restrict__ A)
{
    prep_a_body(blockIdx.x * blockDim.x + threadIdx.x, x, grid, A);
}

__global__ __launch_bounds__(256)
void prep_b_kernel(const float* __restrict__ W, const float* __restrict__ spl,
                   unsigned short* __restrict__ B)
{
    prep_b_body(blockIdx.x * blockDim.x + threadIdx.x, W, spl, B);
}

// ---------------------------------------------------------------------------
// 256x256 tile, BK=64, 8 waves (2M x 4N), split-K=2.
// R10: 2-deep REGISTER software pipeline at half-tile (ks) granularity.
// Two frag sets f0/f1 (static names). Per tile:
//   phase A: MFMA(f0 = frags(u,h0)) || ds_read frags(u,h1) -> f1
//   [LGKM0 VMC0 SBAR]   (one barrier per tile; all waits covered)
//   phase B: MFMA(f1) || ds_read frags(u+1,h0) -> f0 || GLOAD stage(u+2)
// MFMA never waits on same-phase reads; LDS pipe hides under matrix pipe.
// LDS: A0 [0,32K) A1 [32K,64K) B0 [64K,96K) B1 [96K,128K).
//   A row(j) = wr*64 + (j&3)*16 + (j>>2)*128
//   B col(n) = wc*32 + (n&1)*16 + (n>>1)*128
// ---------------------------------------------------------------------------
#define GLOAD(src, dst) __builtin_amdgcn_global_load_lds( \
    (const __attribute__((address_space(1))) void*)(src),  \
    (__attribute__((address_space(3))) void*)(dst), 16, 0, 0)
#define SBAR()  __builtin_amdgcn_s_barrier()
#define SCH0()  __builtin_amdgcn_sched_barrier(0)
#define LGKM0() asm volatile("s_waitcnt lgkmcnt(0)" ::: "memory")
#define VMC0()  asm volatile("s_waitcnt vmcnt(0)" ::: "memory")
#define VMCNT_(n) asm volatile("s_waitcnt vmcnt(" #n ")" ::: "memory")

__global__ __launch_bounds__(512, 2)
void gemm_kan2(const unsigned short* __restrict__ A,
               const unsigned short* __restrict__ B,
               float* __restrict__ P, int rows)
{
    __shared__ char lds[131072];

    const int bid  = blockIdx.x;
    const int sk   = bid & 1;            // XCD = bid&7 owns one (bn,sk) pair:
    const int bn   = (bid >> 1) & 3;     // its 2.36 MB B-panel stays in its L2
    const int bm   = bid >> 3;
    const int tid  = threadIdx.x;
    const int wave = tid >> 6, lane = tid & 63;
    const int wr   = wave >> 2, wc = wave & 3;
    const int fr   = lane & 15, kg = lane >> 4;
    const int sw   = fr & 7;
    const int koff0 = (kg ^ sw) * 16;
    const int koff1 = ((4 | kg) ^ sw) * 16;
    const int k0 = sk * KHALF;

    // staging: thread covers row (tid>>3), 16B chunk (tid&7), inverse-swizzled k
    const int trow = tid >> 3;
    const int ksrc = ((tid & 7) ^ (trow & 7)) * 8;
    const unsigned short* gA = A + (size_t)(bm * 256 + trow) * KTOT + k0 + ksrc;
    const unsigned short* gB = B + (size_t)(bn * 256 + trow) * KTOT + k0 + ksrc;
    const size_t R64 = (size_t)64 * KTOT;

    f32x4 acc[8][4];
    const f32x4 zero = {0.f, 0.f, 0.f, 0.f};
    #pragma unroll
    for (int m = 0; m < 8; ++m)
        #pragma unroll
        for (int n = 0; n < 4; ++n) acc[m][n] = zero;

    // prologue: stage tile 0 -> buf0, tile 1 -> buf1
    {
        char* dA = lds + tid * 16;
        char* dB = lds + 65536 + tid * 16;
        GLOAD(gA,           dA);           GLOAD(gA + R64,     dA + 8192);
        GLOAD(gA + 2 * R64, dA + 16384);   GLOAD(gA + 3 * R64, dA + 24576);
        GLOAD(gB,           dB);           GLOAD(gB + R64,     dB + 8192);
        GLOAD(gB + 2 * R64, dB + 16384);   GLOAD(gB + 3 * R64, dB + 24576);
        gA += 64; gB += 64;
        dA += 32768; dB += 32768;
        GLOAD(gA,           dA);           GLOAD(gA + R64,     dA + 8192);
        GLOAD(gA + 2 * R64, dA + 16384);   GLOAD(gA + 3 * R64, dA + 24576);
        GLOAD(gB,           dB);           GLOAD(gB + R64,     dB + 8192);
        GLOAD(gB + 2 * R64, dB + 16384);   GLOAD(gB + 3 * R64, dB + 24576);
        gA += 64; gB += 64;
    }
    VMCNT_(8); SBAR(); SCH0();   // tile 0 resident (tile 1 still in flight)

    const int aOff = (wr * 64 + fr) * 128;            // + (j&3)*2048 + (j>>2)*16384
    const int bOff = 65536 + (wc * 32 + fr) * 128;    // + (n&1)*2048 + (n>>1)*16384

    bf16x8 af0[8], bf0[4], af1[8], bf1[4];

    // preload frags(0,h0) -> f0
    #pragma unroll
    for (int j = 0; j < 8; ++j)
        af0[j] = *(const bf16x8*)(lds + aOff + (j & 3) * 2048 + (j >> 2) * 16384 + koff0);
    #pragma unroll
    for (int n = 0; n < 4; ++n)
        bf0[n] = *(const bf16x8*)(lds + bOff + (n & 1) * 2048 + (n >> 1) * 16384 + koff0);

    int u = 0;

    // MODE: 0 = steady (stage u+2, read u+1); 1 = u==70 (read u+1, no stage);
    //       2 = u==71 (last: no reads, no stage)
    auto tile = [&](auto mC) {
        constexpr int MODE = decltype(mC)::value;
        char* bufAc = lds + (u & 1) * 32768;
        char* bufBc = bufAc + 65536;
        char* bufAn = lds + ((u & 1) ^ 1) * 32768;
        char* bufBn = bufAn + 65536;

        // ---- phase A: read frags(u,h1)->f1 ; MFMA f0 ----
        #pragma unroll
        for (int j = 0; j < 8; ++j)
            af1[j] = *(const bf16x8*)(bufAc + aOff + (j & 3) * 2048 + (j >> 2) * 16384 + koff1);
        #pragma unroll
        for (int n = 0; n < 4; ++n)
            bf1[n] = *(const bf16x8*)(bufBc + bOff - 65536 + (n & 1) * 2048 + (n >> 1) * 16384 + koff1);
        __builtin_amdgcn_s_setprio(1);
        #pragma unroll
        for (int j = 0; j < 8; ++j)
            #pragma unroll
            for (int n = 0; n < 4; ++n)
                acc[j][n] = __builtin_amdgcn_mfma_f32_16x16x32_bf16(
                    af0[j], bf0[n], acc[j][n], 0, 0, 0);
        __builtin_amdgcn_s_setprio(0);

        SCH0(); LGKM0(); VMC0(); SBAR(); SCH0();
        // my phase-A reads done; my stage(u+1) gloads drained; after the
        // barrier ALL waves' stage(u+1) is resident and buf(u) reads closed.

        // ---- phase B: read frags(u+1,h0)->f0 ; stage(u+2); MFMA f1 ----
        if constexpr (MODE <= 1) {
            #pragma unroll
            for (int j = 0; j < 8; ++j)
                af0[j] = *(const bf16x8*)(bufAn + aOff + (j & 3) * 2048 + (j >> 2) * 16384 + koff0);
            #pragma unroll
            for (int n = 0; n < 4; ++n)
                bf0[n] = *(const bf16x8*)(bufBn + bOff - 65536 + (n & 1) * 2048 + (n >> 1) * 16384 + koff0);
        }
        if constexpr (MODE == 0) {
            char* dA = bufAc + tid * 16;
            char* dB = bufBc + tid * 16;
            GLOAD(gA,           dA);           GLOAD(gA + R64,     dA + 8192);
            GLOAD(gA + 2 * R64, dA + 16384);   GLOAD(gA + 3 * R64, dA + 24576);
            GLOAD(gB,           dB);           GLOAD(gB + R64,     dB + 8192);
            GLOAD(gB + 2 * R64, dB + 16384);   GLOAD(gB + 3 * R64, dB + 24576);
            gA += 64; gB += 64;
        }
        __builtin_amdgcn_s_setprio(1);
        #pragma unroll
        for (int j = 0; j < 8; ++j)
            #pragma unroll
            for (int n = 0; n < 4; ++n)
                acc[j][n] = __builtin_amdgcn_mfma_f32_16x16x32_bf16(
                    af1[j], bf1[n], acc[j][n], 0, 0, 0);
        __builtin_amdgcn_s_setprio(0);
        // no tile-end barrier: next tile's phase A touches only buf(u+1)
        // (resident) and f0 (read this phase, same wave, compiler lgkm).
    };

    for (u = 0; u < NTILE - 2; ++u) tile(ModeT<0>{});
    tile(ModeT<1>{});   // u == 70
    ++u;
    tile(ModeT<2>{});   // u == 71

    // epilogue: write f32 partials (interleaved-quadrant mapping)
    float* Pp = P + (size_t)sk * rows * OUT_F;
    const size_t orow0 = (size_t)bm * 256 + (size_t)wr * 64;
    const int    ocol0 = bn * 256 + wc * 32;
    #pragma unroll
    for (int n = 0; n < 4; ++n) {
        const int col = ocol0 + (n & 1) * 16 + (n >> 1) * 128 + fr;
        #pragma unroll
        for (int m = 0; m < 8; ++m) {
            const size_t r0 = orow0 + (m & 3) * 16 + (m >> 2) * 128 + kg * 4;
            #pragma unroll
            for (int j2 = 0; j2 < 4; ++j2)
                Pp[(r0 + j2) * OUT_F + col] = acc[m][n][j2];
        }
    }
}

// out = P0 + P1 + bias
__global__ __launch_bounds__(256)
void reduce_kan(const float* __restrict__ P, const float* __restrict__ bias,
                float* __restrict__ out, int n4, int skStride4)
{
    const float4* p0 = (const float4*)P;
    const float4* p1 = p0 + skStride4;
    const float4* bv = (const float4*)bias;
    float4* o = (float4*)out;
    for (int i = blockIdx.x * blockDim.x + threadIdx.x; i < n4;
         i += gridDim.x * blockDim.x) {
        float4 a = p0[i], b = p1[i], c = bv[i & 255];
        float4 r;
        r.x = a.x + b.x + c.x;  r.y = a.y + b.y + c.y;
        r.z = a.z + b.z + c.z;  r.w = a.w + b.w + c.w;
        o[i] = r;
    }
}

extern "C" void kernel_launch(void* const* d_in, const int* in_sizes, int n_in,
                              void* d_out, int out_size, void* d_ws, size_t ws_size,
                              hipStream_t stream)
{
    const float* x    = (const float*)d_in[0];
    const float* W    = (const float*)d_in[1];
    const float* bias = (const float*)d_in[2];
    const float* spl  = (const float*)d_in[3];
    const float* grid = (const float*)d_in[4];
    float* out = (float*)d_out;

    unsigned short* Bw = (unsigned short*)d_ws;               // 18.9 MB
    unsigned short* Aw = Bw + (size_t)OUT_F * KTOT;

    // per-row ws: A bf16 (18432 B) + 2x f32 partial (8192 B)
    const size_t bBytes = (size_t)OUT_F * KTOT * 2;
    size_t avail = ws_size > bBytes ? ws_size - bBytes : 0;
    long maxRows = (long)(avail / 26624);
    int chunk = (maxRows >= TOKENS) ? TOKENS : (int)((maxRows / 256) * 256);
    if (chunk < 256) chunk = 256;
    float* Pp = (float*)(Aw + (size_t)chunk * KTOT);

    if (chunk == TOKENS) {
        // fused prep (A + B in one BW-bound sweep), then one GEMM + reduce
        prep_fused<<<(TOKENS * IN_F) / 256 + (OUT_F * (KTOT / 8)) / 256,
                     256, 0, stream>>>(x, grid, W, spl, Aw, Bw);
        gemm_kan2<<<(TOKENS >> 8) * 8, 512, 0, stream>>>(Aw, Bw, Pp, TOKENS);
        int n4 = TOKENS * 256;
        reduce_kan<<<2048, 256, 0, stream>>>(Pp, bias, out, n4, n4);
    } else {
        prep_b_kernel<<<(OUT_F * (KTOT / 8)) / 256, 256, 0, stream>>>(W, spl, Bw);
        for (int t0 = 0; t0 < TOKENS; t0 += chunk) {
            int rows = (TOKENS - t0 < chunk) ? (TOKENS - t0) : chunk;
            prep_a_kernel<<<(rows * IN_F) / 256, 256, 0, stream>>>(
                x + (size_t)t0 * IN_F, grid, Aw);
            gemm_kan2<<<(rows >> 8) * 8, 512, 0, stream>>>(Aw, Bw, Pp, rows);
            int n4 = rows * 256;
            int rblocks = (n4 + 255) / 256; if (rblocks > 2048) rblocks = 2048;
            reduce_kan<<<rblocks, 256, 0, stream>>>(
                Pp, bias, out + (size_t)t0 * OUT_F, n4, n4);
        }
    }
}

// Round 11
// 180.405 us; speedup vs baseline: 1.4556x; 1.0718x over previous
//
#include <hip/hip_runtime.h>
#include <hip/hip_bf16.h>

#define IN_F   1024
#define OUT_F  1024
#define TOKENS 8192
#define KTOT   9216
#define KHALF  4608
#define NTILE  72          // KHALF / 64

typedef __attribute__((ext_vector_type(8))) short  bf16x8;
typedef __attribute__((ext_vector_type(8))) unsigned short ushortx8;
typedef __attribute__((ext_vector_type(4))) float  f32x4;

template<int M> struct ModeT { static constexpr int value = M; };

__device__ __forceinline__ unsigned int f2bf(float f) {
    union { float f; unsigned int u; } v; v.f = f;
    unsigned int r = v.u + 0x7fffu + ((v.u >> 16) & 1u);
    return r >> 16;
}

__device__ __forceinline__ float bf2f(unsigned short h) {
    union { unsigned int u; float f; } v; v.u = ((unsigned int)h) << 16;
    return v.f;
}

__device__ __forceinline__ void prep_a_body(int idx, const float* __restrict__ x,
                                            const float* __restrict__ grid,
                                            unsigned short* __restrict__ A)
{
    int t = idx >> 10;
    int i = idx & 1023;
    float xv = x[idx];
    float sil = xv / (1.0f + __expf(-xv));
    A[(size_t)t * KTOT + i] = (unsigned short)f2bf(sil);

    const float invd = 1.0f / (2.0f / 7.0f + 1e-5f);
    unsigned int h[8];
    #pragma unroll
    for (int g = 0; g < 8; ++g) {
        float d = (xv - grid[g]) * invd;
        h[g] = f2bf(__expf(-d * d));
    }
    uint4 pk;
    pk.x = h[0] | (h[1] << 16);
    pk.y = h[2] | (h[3] << 16);
    pk.z = h[4] | (h[5] << 16);
    pk.w = h[6] | (h[7] << 16);
    *reinterpret_cast<uint4*>(&A[(size_t)t * KTOT + IN_F + (size_t)i * 8]) = pk;
}

__device__ __forceinline__ void prep_b_body(int idx, const float* __restrict__ W,
                                            const float* __restrict__ spl,
                                            unsigned short* __restrict__ B)
{
    int o  = idx / (KTOT / 8);
    int c8 = idx - o * (KTOT / 8);
    const float* src = (c8 < IN_F / 8)
        ? (W   + (size_t)o * IN_F     + (size_t)c8 * 8)
        : (spl + (size_t)o * IN_F * 8 + (size_t)(c8 - IN_F / 8) * 8);
    const float4* s4 = reinterpret_cast<const float4*>(src);
    float4 lo = s4[0], hi = s4[1];
    uint4 pk;
    pk.x = f2bf(lo.x) | (f2bf(lo.y) << 16);
    pk.y = f2bf(lo.z) | (f2bf(lo.w) << 16);
    pk.z = f2bf(hi.x) | (f2bf(hi.y) << 16);
    pk.w = f2bf(hi.z) | (f2bf(hi.w) << 16);
    *reinterpret_cast<uint4*>(&B[(size_t)o * KTOT + (size_t)c8 * 8]) = pk;
}

// Fused A+B prep: blocks [0, 32768) build A (silu + basis), rest repack B.
__global__ __launch_bounds__(256)
void prep_fused(const float* __restrict__ x, const float* __restrict__ grid,
                const float* __restrict__ W, const float* __restrict__ spl,
                unsigned short* __restrict__ A, unsigned short* __restrict__ B)
{
    int b = blockIdx.x;
    if (b < (TOKENS * IN_F) / 256)
        prep_a_body(b * 256 + threadIdx.x, x, grid, A);
    else
        prep_b_body((b - (TOKENS * IN_F) / 256) * 256 + threadIdx.x, W, spl, B);
}

__global__ __launch_bounds__(256)
void prep_a_kernel(const float* __restrict__ x, const float* __restrict__ grid,
                   unsigned short* __restrict__ A)
{
    prep_a_body(blockIdx.x * blockDim.x + threadIdx.x, x, grid, A);
}

__global__ __launch_bounds__(256)
void prep_b_kernel(const float* __restrict__ W, const float* __restrict__ spl,
                   unsigned short* __restrict__ B)
{
    prep_b_body(blockIdx.x * blockDim.x + threadIdx.x, W, spl, B);
}

// ---------------------------------------------------------------------------
// 256x256 tile, BK=64, 8 waves (2M x 4N), split-K=2.
// R6 barrier-minimal body (best proven: 138 us, MfmaUtil 49, 0 conflicts):
// one s_barrier + one vmcnt(0) per K-tile, 64 MFMA between barriers,
// natural compiler scheduling. R11: partials written as BF16 (halves
// epilogue write + reduce traffic; |P|<~8 -> quantum <=0.031, safe vs 0.153).
//   A row(mi) = wr*64 + (mi&3)*16 + (mi>>2)*128
//   B col(ni) = wc*32 + (ni&1)*16 + (ni>>1)*128
// ---------------------------------------------------------------------------
#define GLOAD(src, dst) __builtin_amdgcn_global_load_lds( \
    (const __attribute__((address_space(1))) void*)(src),  \
    (__attribute__((address_space(3))) void*)(dst), 16, 0, 0)
#define SBAR()  __builtin_amdgcn_s_barrier()
#define SCH0()  __builtin_amdgcn_sched_barrier(0)
#define VMC0()  asm volatile("s_waitcnt vmcnt(0)" ::: "memory")

__global__ __launch_bounds__(512, 2)
void gemm_kan2(const unsigned short* __restrict__ A,
               const unsigned short* __restrict__ B,
               unsigned short* __restrict__ P, int rows)
{
    __shared__ char lds[131072];   // A dbuf [0,64K), B dbuf [64K,128K)

    const int bid  = blockIdx.x;
    const int sk   = bid & 1;            // XCD = bid&7 owns one (bn,sk) pair:
    const int bn   = (bid >> 1) & 3;     // its 2.36 MB B-panel stays in its L2
    const int bm   = bid >> 3;
    const int tid  = threadIdx.x;
    const int wave = tid >> 6, lane = tid & 63;
    const int wr   = wave >> 2, wc = wave & 3;
    const int fr   = lane & 15, kg = lane >> 4;
    const int sw   = fr & 7;
    const int koff[2] = { (kg ^ sw) * 16, ((4 | kg) ^ sw) * 16 };
    const int k0 = sk * KHALF;

    // staging: thread covers row (tid>>3), 16B chunk (tid&7), inverse-swizzled k
    const int trow = tid >> 3;
    const int ksrc = ((tid & 7) ^ (trow & 7)) * 8;
    const unsigned short* gA = A + (size_t)(bm * 256 + trow) * KTOT + k0 + ksrc;
    const unsigned short* gB = B + (size_t)(bn * 256 + trow) * KTOT + k0 + ksrc;
    const size_t R64 = (size_t)64 * KTOT;

    f32x4 acc[8][4];
    const f32x4 zero = {0.f, 0.f, 0.f, 0.f};
    #pragma unroll
    for (int m = 0; m < 8; ++m)
        #pragma unroll
        for (int n = 0; n < 4; ++n) acc[m][n] = zero;

    // prologue: stage tile 0 -> buf0
    {
        char* dA = lds + tid * 16;
        char* dB = lds + 65536 + tid * 16;
        GLOAD(gA,           dA);           GLOAD(gA + R64,     dA + 8192);
        GLOAD(gA + 2 * R64, dA + 16384);   GLOAD(gA + 3 * R64, dA + 24576);
        GLOAD(gB,           dB);           GLOAD(gB + R64,     dB + 8192);
        GLOAD(gB + 2 * R64, dB + 16384);   GLOAD(gB + 3 * R64, dB + 24576);
        gA += 64; gB += 64;
    }
    VMC0(); SBAR(); SCH0();

    const int aOff = (wr * 64 + fr) * 128;   // + (mi&3)*2048; +16384 for hi half
    const int bOff = (wc * 32 + fr) * 128;   // + (ni&1)*2048; +16384 for hi half

    bf16x8 af[4][2], bfLo[2][2], bfHi[2][2];
    int u = 0;

    // MODE: 0 = steady (stages tile u+1), 1 = last tile (no staging)
    auto tile = [&](auto mC) {
        constexpr int MODE = decltype(mC)::value;
        char* bufA = lds + (u & 1) * 32768;
        char* bufB = lds + 65536 + (u & 1) * 32768;

        // ---- reads: af-lo, bfLo, bfHi (16 x ds_read_b128) ----
        #pragma unroll
        for (int mi = 0; mi < 4; ++mi)
            #pragma unroll
            for (int ks = 0; ks < 2; ++ks)
                af[mi][ks] = *(const bf16x8*)(bufA + aOff + mi * 2048 + koff[ks]);
        #pragma unroll
        for (int ni = 0; ni < 2; ++ni)
            #pragma unroll
            for (int ks = 0; ks < 2; ++ks) {
                bfLo[ni][ks] = *(const bf16x8*)(bufB + bOff + ni * 2048 + koff[ks]);
                bfHi[ni][ks] = *(const bf16x8*)(bufB + bOff + 16384 + ni * 2048 + koff[ks]);
            }

        // ---- stage tile u+1 into the other buffers ----
        if constexpr (MODE == 0) {
            char* dA = lds + ((u & 1) ^ 1) * 32768 + tid * 16;
            char* dB = lds + 65536 + ((u & 1) ^ 1) * 32768 + tid * 16;
            GLOAD(gA,           dA);           GLOAD(gA + R64,     dA + 8192);
            GLOAD(gA + 2 * R64, dA + 16384);   GLOAD(gA + 3 * R64, dA + 24576);
            GLOAD(gB,           dB);           GLOAD(gB + R64,     dB + 8192);
            GLOAD(gB + 2 * R64, dB + 16384);   GLOAD(gB + 3 * R64, dB + 24576);
            gA += 64; gB += 64;
        }
        SCH0();

        // ---- q00: af-lo x bfLo ----
        __builtin_amdgcn_s_setprio(1);
        #pragma unroll
        for (int mi = 0; mi < 4; ++mi)
            #pragma unroll
            for (int ni = 0; ni < 2; ++ni)
                #pragma unroll
                for (int ks = 0; ks < 2; ++ks)
                    acc[mi][ni] = __builtin_amdgcn_mfma_f32_16x16x32_bf16(
                        af[mi][ks], bfLo[ni][ks], acc[mi][ni], 0, 0, 0);
        __builtin_amdgcn_s_setprio(0);

        // ---- q01: af-lo x bfHi ----
        __builtin_amdgcn_s_setprio(1);
        #pragma unroll
        for (int mi = 0; mi < 4; ++mi)
            #pragma unroll
            for (int ni = 0; ni < 2; ++ni)
                #pragma unroll
                for (int ks = 0; ks < 2; ++ks)
                    acc[mi][2 + ni] = __builtin_amdgcn_mfma_f32_16x16x32_bf16(
                        af[mi][ks], bfHi[ni][ks], acc[mi][2 + ni], 0, 0, 0);
        __builtin_amdgcn_s_setprio(0);

        // ---- af-hi reads (8 x ds_read_b128), overlap q01 drain ----
        #pragma unroll
        for (int mi = 0; mi < 4; ++mi)
            #pragma unroll
            for (int ks = 0; ks < 2; ++ks)
                af[mi][ks] = *(const bf16x8*)(bufA + aOff + 16384 + mi * 2048 + koff[ks]);

        // ---- q10: af-hi x bfLo ----
        __builtin_amdgcn_s_setprio(1);
        #pragma unroll
        for (int mi = 0; mi < 4; ++mi)
            #pragma unroll
            for (int ni = 0; ni < 2; ++ni)
                #pragma unroll
                for (int ks = 0; ks < 2; ++ks)
                    acc[4 + mi][ni] = __builtin_amdgcn_mfma_f32_16x16x32_bf16(
                        af[mi][ks], bfLo[ni][ks], acc[4 + mi][ni], 0, 0, 0);
        __builtin_amdgcn_s_setprio(0);

        // ---- q11: af-hi x bfHi ----
        __builtin_amdgcn_s_setprio(1);
        #pragma unroll
        for (int mi = 0; mi < 4; ++mi)
            #pragma unroll
            for (int ni = 0; ni < 2; ++ni)
                #pragma unroll
                for (int ks = 0; ks < 2; ++ks)
                    acc[4 + mi][2 + ni] = __builtin_amdgcn_mfma_f32_16x16x32_bf16(
                        af[mi][ks], bfHi[ni][ks], acc[4 + mi][2 + ni], 0, 0, 0);
        __builtin_amdgcn_s_setprio(0);

        SCH0();
        if constexpr (MODE == 0) {
            VMC0();          // tile u+1 resident (issued a full tile ago)
            SBAR(); SCH0();  // all waves done reading buf(u); safe to overwrite next
        }
    };

    for (u = 0; u < NTILE - 1; ++u) tile(ModeT<0>{});
    tile(ModeT<1>{});

    // epilogue: write BF16 partials (interleaved-quadrant mapping)
    unsigned short* Pp = P + (size_t)sk * rows * OUT_F;
    const size_t orow0 = (size_t)bm * 256 + (size_t)wr * 64;
    const int    ocol0 = bn * 256 + wc * 32;
    #pragma unroll
    for (int n = 0; n < 4; ++n) {
        const int col = ocol0 + (n & 1) * 16 + (n >> 1) * 128 + fr;
        #pragma unroll
        for (int m = 0; m < 8; ++m) {
            const size_t r0 = orow0 + (m & 3) * 16 + (m >> 2) * 128 + kg * 4;
            #pragma unroll
            for (int j2 = 0; j2 < 4; ++j2)
                Pp[(r0 + j2) * OUT_F + col] = (unsigned short)f2bf(acc[m][n][j2]);
        }
    }
}

// out = P0 + P1 + bias   (bf16 partials, f32 out; 8 elems/thread)
__global__ __launch_bounds__(256)
void reduce_kan(const unsigned short* __restrict__ P,
                const float* __restrict__ bias,
                float* __restrict__ out, int n8, int skStride8)
{
    const ushortx8* p0 = (const ushortx8*)P;
    const ushortx8* p1 = p0 + skStride8;
    const float4* bv = (const float4*)bias;
    float4* o = (float4*)out;
    for (int i = blockIdx.x * blockDim.x + threadIdx.x; i < n8;
         i += gridDim.x * blockDim.x) {
        ushortx8 a = p0[i], b = p1[i];
        float4 c0 = bv[(i & 127) * 2], c1 = bv[(i & 127) * 2 + 1];
        float4 r0, r1;
        r0.x = bf2f(a[0]) + bf2f(b[0]) + c0.x;
        r0.y = bf2f(a[1]) + bf2f(b[1]) + c0.y;
        r0.z = bf2f(a[2]) + bf2f(b[2]) + c0.z;
        r0.w = bf2f(a[3]) + bf2f(b[3]) + c0.w;
        r1.x = bf2f(a[4]) + bf2f(b[4]) + c1.x;
        r1.y = bf2f(a[5]) + bf2f(b[5]) + c1.y;
        r1.z = bf2f(a[6]) + bf2f(b[6]) + c1.z;
        r1.w = bf2f(a[7]) + bf2f(b[7]) + c1.w;
        o[i * 2]     = r0;
        o[i * 2 + 1] = r1;
    }
}

extern "C" void kernel_launch(void* const* d_in, const int* in_sizes, int n_in,
                              void* d_out, int out_size, void* d_ws, size_t ws_size,
                              hipStream_t stream)
{
    const float* x    = (const float*)d_in[0];
    const float* W    = (const float*)d_in[1];
    const float* bias = (const float*)d_in[2];
    const float* spl  = (const float*)d_in[3];
    const float* grid = (const float*)d_in[4];
    float* out = (float*)d_out;

    unsigned short* Bw = (unsigned short*)d_ws;               // 18.9 MB
    unsigned short* Aw = Bw + (size_t)OUT_F * KTOT;

    // per-row ws: A bf16 (18432 B) + 2x bf16 partial (4096 B) = 22528 B
    const size_t bBytes = (size_t)OUT_F * KTOT * 2;
    size_t avail = ws_size > bBytes ? ws_size - bBytes : 0;
    long maxRows = (long)(avail / 22528);
    int chunk = (maxRows >= TOKENS) ? TOKENS : (int)((maxRows / 256) * 256);
    if (chunk < 256) chunk = 256;
    unsigned short* Pp = Aw + (size_t)chunk * KTOT;

    if (chunk == TOKENS) {
        // fused prep (A + B in one BW-bound sweep), then one GEMM + reduce
        prep_fused<<<(TOKENS * IN_F) / 256 + (OUT_F * (KTOT / 8)) / 256,
                     256, 0, stream>>>(x, grid, W, spl, Aw, Bw);
        gemm_kan2<<<(TOKENS >> 8) * 8, 512, 0, stream>>>(Aw, Bw, Pp, TOKENS);
        int n8 = TOKENS * 128;
        reduce_kan<<<2048, 256, 0, stream>>>(Pp, bias, out, n8, n8);
    } else {
        prep_b_kernel<<<(OUT_F * (KTOT / 8)) / 256, 256, 0, stream>>>(W, spl, Bw);
        for (int t0 = 0; t0 < TOKENS; t0 += chunk) {
            int rows = (TOKENS - t0 < chunk) ? (TOKENS - t0) : chunk;
            prep_a_kernel<<<(rows * IN_F) / 256, 256, 0, stream>>>(
                x + (size_t)t0 * IN_F, grid, Aw);
            gemm_kan2<<<(rows >> 8) * 8, 512, 0, stream>>>(Aw, Bw, Pp, rows);
            int n8 = rows * 128;
            int rblocks = (n8 + 255) / 256; if (rblocks > 2048) rblocks = 2048;
            reduce_kan<<<rblocks, 256, 0, stream>>>(
                Pp, bias, out + (size_t)t0 * OUT_F, n8, n8);
        }
    }
}

// Round 12
// 175.514 us; speedup vs baseline: 1.4962x; 1.0279x over previous
//
#include <hip/hip_runtime.h>
#include <hip/hip_bf16.h>

#define IN_F   1024
#define OUT_F  1024
#define TOKENS 8192
#define KTOT   9216
#define KHALF  4608
#define NTILE  72          // KHALF / 64

typedef __attribute__((ext_vector_type(8))) short  bf16x8;
typedef __attribute__((ext_vector_type(8))) unsigned short ushortx8;
typedef __attribute__((ext_vector_type(4))) float  f32x4;

template<int M> struct ModeT { static constexpr int value = M; };

__device__ __forceinline__ unsigned int f2bf(float f) {
    union { float f; unsigned int u; } v; v.f = f;
    unsigned int r = v.u + 0x7fffu + ((v.u >> 16) & 1u);
    return r >> 16;
}

__device__ __forceinline__ float bf2f(unsigned short h) {
    union { unsigned int u; float f; } v; v.u = ((unsigned int)h) << 16;
    return v.f;
}

__device__ __forceinline__ void prep_a_body(int idx, const float* __restrict__ x,
                                            const float* __restrict__ grid,
                                            unsigned short* __restrict__ A)
{
    int t = idx >> 10;
    int i = idx & 1023;
    float xv = x[idx];
    float sil = xv / (1.0f + __expf(-xv));
    A[(size_t)t * KTOT + i] = (unsigned short)f2bf(sil);

    const float invd = 1.0f / (2.0f / 7.0f + 1e-5f);
    unsigned int h[8];
    #pragma unroll
    for (int g = 0; g < 8; ++g) {
        float d = (xv - grid[g]) * invd;
        h[g] = f2bf(__expf(-d * d));
    }
    uint4 pk;
    pk.x = h[0] | (h[1] << 16);
    pk.y = h[2] | (h[3] << 16);
    pk.z = h[4] | (h[5] << 16);
    pk.w = h[6] | (h[7] << 16);
    *reinterpret_cast<uint4*>(&A[(size_t)t * KTOT + IN_F + (size_t)i * 8]) = pk;
}

__device__ __forceinline__ void prep_b_body(int idx, const float* __restrict__ W,
                                            const float* __restrict__ spl,
                                            unsigned short* __restrict__ B)
{
    int o  = idx / (KTOT / 8);
    int c8 = idx - o * (KTOT / 8);
    const float* src = (c8 < IN_F / 8)
        ? (W   + (size_t)o * IN_F     + (size_t)c8 * 8)
        : (spl + (size_t)o * IN_F * 8 + (size_t)(c8 - IN_F / 8) * 8);
    const float4* s4 = reinterpret_cast<const float4*>(src);
    float4 lo = s4[0], hi = s4[1];
    uint4 pk;
    pk.x = f2bf(lo.x) | (f2bf(lo.y) << 16);
    pk.y = f2bf(lo.z) | (f2bf(lo.w) << 16);
    pk.z = f2bf(hi.x) | (f2bf(hi.y) << 16);
    pk.w = f2bf(hi.z) | (f2bf(hi.w) << 16);
    *reinterpret_cast<uint4*>(&B[(size_t)o * KTOT + (size_t)c8 * 8]) = pk;
}

// Fused A+B prep: blocks [0, 32768) build A (silu + basis), rest repack B.
__global__ __launch_bounds__(256)
void prep_fused(const float* __restrict__ x, const float* __restrict__ grid,
                const float* __restrict__ W, const float* __restrict__ spl,
                unsigned short* __restrict__ A, unsigned short* __restrict__ B)
{
    int b = blockIdx.x;
    if (b < (TOKENS * IN_F) / 256)
        prep_a_body(b * 256 + threadIdx.x, x, grid, A);
    else
        prep_b_body((b - (TOKENS * IN_F) / 256) * 256 + threadIdx.x, W, spl, B);
}

__global__ __launch_bounds__(256)
void prep_a_kernel(const float* __restrict__ x, const float* __restrict__ grid,
                   unsigned short* __restrict__ A)
{
    prep_a_body(blockIdx.x * blockDim.x + threadIdx.x, x, grid, A);
}

__global__ __launch_bounds__(256)
void prep_b_kernel(const float* __restrict__ W, const float* __restrict__ spl,
                   unsigned short* __restrict__ B)
{
    prep_b_body(blockIdx.x * blockDim.x + threadIdx.x, W, spl, B);
}

// ---------------------------------------------------------------------------
// 256x256 tile, BK=64, 8 waves (2M x 4N), split-K=2.
// R6/R11 barrier-minimal body (best proven: gemm 128 us, MfmaUtil 54%,
// 0 bank conflicts): one s_barrier + one vmcnt(0) per K-tile, 64 MFMA
// between barriers, natural compiler scheduling; BF16 partials.
// R12: + R8's A-locality XCD remap (proven FETCH 304->155 MB, wall-neutral):
// bm = xcd (mod 8), so all 8 (bn,sk) siblings of one bm co-reside on one XCD
// and its L2 serves the 7 sibling A re-reads.
//   A row(mi) = wr*64 + (mi&3)*16 + (mi>>2)*128
//   B col(ni) = wc*32 + (ni&1)*16 + (ni>>1)*128
// ---------------------------------------------------------------------------
#define GLOAD(src, dst) __builtin_amdgcn_global_load_lds( \
    (const __attribute__((address_space(1))) void*)(src),  \
    (__attribute__((address_space(3))) void*)(dst), 16, 0, 0)
#define SBAR()  __builtin_amdgcn_s_barrier()
#define SCH0()  __builtin_amdgcn_sched_barrier(0)
#define VMC0()  asm volatile("s_waitcnt vmcnt(0)" ::: "memory")

__global__ __launch_bounds__(512, 2)
void gemm_kan2(const unsigned short* __restrict__ A,
               const unsigned short* __restrict__ B,
               unsigned short* __restrict__ P, int rows)
{
    __shared__ char lds[131072];   // A dbuf [0,64K), B dbuf [64K,128K)

    const int bid  = blockIdx.x;
    // A-locality remap (R8-proven): xcd = bid&7 (round-robin dispatch);
    // bm == xcd (mod 8) -> the 8 (bn,sk) siblings of one bm share one XCD's L2.
    const int xcd  = bid & 7;
    const int j    = bid >> 3;
    const int sk   = j & 1;
    const int bn   = (j >> 1) & 3;
    const int bm   = (j >> 3) * 8 + xcd;
    const int tid  = threadIdx.x;
    const int wave = tid >> 6, lane = tid & 63;
    const int wr   = wave >> 2, wc = wave & 3;
    const int fr   = lane & 15, kg = lane >> 4;
    const int sw   = fr & 7;
    const int koff[2] = { (kg ^ sw) * 16, ((4 | kg) ^ sw) * 16 };
    const int k0 = sk * KHALF;

    // staging: thread covers row (tid>>3), 16B chunk (tid&7), inverse-swizzled k
    const int trow = tid >> 3;
    const int ksrc = ((tid & 7) ^ (trow & 7)) * 8;
    const unsigned short* gA = A + (size_t)(bm * 256 + trow) * KTOT + k0 + ksrc;
    const unsigned short* gB = B + (size_t)(bn * 256 + trow) * KTOT + k0 + ksrc;
    const size_t R64 = (size_t)64 * KTOT;

    f32x4 acc[8][4];
    const f32x4 zero = {0.f, 0.f, 0.f, 0.f};
    #pragma unroll
    for (int m = 0; m < 8; ++m)
        #pragma unroll
        for (int n = 0; n < 4; ++n) acc[m][n] = zero;

    // prologue: stage tile 0 -> buf0
    {
        char* dA = lds + tid * 16;
        char* dB = lds + 65536 + tid * 16;
        GLOAD(gA,           dA);           GLOAD(gA + R64,     dA + 8192);
        GLOAD(gA + 2 * R64, dA + 16384);   GLOAD(gA + 3 * R64, dA + 24576);
        GLOAD(gB,           dB);           GLOAD(gB + R64,     dB + 8192);
        GLOAD(gB + 2 * R64, dB + 16384);   GLOAD(gB + 3 * R64, dB + 24576);
        gA += 64; gB += 64;
    }
    VMC0(); SBAR(); SCH0();

    const int aOff = (wr * 64 + fr) * 128;   // + (mi&3)*2048; +16384 for hi half
    const int bOff = (wc * 32 + fr) * 128;   // + (ni&1)*2048; +16384 for hi half

    bf16x8 af[4][2], bfLo[2][2], bfHi[2][2];
    int u = 0;

    // MODE: 0 = steady (stages tile u+1), 1 = last tile (no staging)
    auto tile = [&](auto mC) {
        constexpr int MODE = decltype(mC)::value;
        char* bufA = lds + (u & 1) * 32768;
        char* bufB = lds + 65536 + (u & 1) * 32768;

        // ---- reads: af-lo, bfLo, bfHi (16 x ds_read_b128) ----
        #pragma unroll
        for (int mi = 0; mi < 4; ++mi)
            #pragma unroll
            for (int ks = 0; ks < 2; ++ks)
                af[mi][ks] = *(const bf16x8*)(bufA + aOff + mi * 2048 + koff[ks]);
        #pragma unroll
        for (int ni = 0; ni < 2; ++ni)
            #pragma unroll
            for (int ks = 0; ks < 2; ++ks) {
                bfLo[ni][ks] = *(const bf16x8*)(bufB + bOff + ni * 2048 + koff[ks]);
                bfHi[ni][ks] = *(const bf16x8*)(bufB + bOff + 16384 + ni * 2048 + koff[ks]);
            }

        // ---- stage tile u+1 into the other buffers ----
        if constexpr (MODE == 0) {
            char* dA = lds + ((u & 1) ^ 1) * 32768 + tid * 16;
            char* dB = lds + 65536 + ((u & 1) ^ 1) * 32768 + tid * 16;
            GLOAD(gA,           dA);           GLOAD(gA + R64,     dA + 8192);
            GLOAD(gA + 2 * R64, dA + 16384);   GLOAD(gA + 3 * R64, dA + 24576);
            GLOAD(gB,           dB);           GLOAD(gB + R64,     dB + 8192);
            GLOAD(gB + 2 * R64, dB + 16384);   GLOAD(gB + 3 * R64, dB + 24576);
            gA += 64; gB += 64;
        }
        SCH0();

        // ---- q00: af-lo x bfLo ----
        __builtin_amdgcn_s_setprio(1);
        #pragma unroll
        for (int mi = 0; mi < 4; ++mi)
            #pragma unroll
            for (int ni = 0; ni < 2; ++ni)
                #pragma unroll
                for (int ks = 0; ks < 2; ++ks)
                    acc[mi][ni] = __builtin_amdgcn_mfma_f32_16x16x32_bf16(
                        af[mi][ks], bfLo[ni][ks], acc[mi][ni], 0, 0, 0);
        __builtin_amdgcn_s_setprio(0);

        // ---- q01: af-lo x bfHi ----
        __builtin_amdgcn_s_setprio(1);
        #pragma unroll
        for (int mi = 0; mi < 4; ++mi)
            #pragma unroll
            for (int ni = 0; ni < 2; ++ni)
                #pragma unroll
                for (int ks = 0; ks < 2; ++ks)
                    acc[mi][2 + ni] = __builtin_amdgcn_mfma_f32_16x16x32_bf16(
                        af[mi][ks], bfHi[ni][ks], acc[mi][2 + ni], 0, 0, 0);
        __builtin_amdgcn_s_setprio(0);

        // ---- af-hi reads (8 x ds_read_b128), overlap q01 drain ----
        #pragma unroll
        for (int mi = 0; mi < 4; ++mi)
            #pragma unroll
            for (int ks = 0; ks < 2; ++ks)
                af[mi][ks] = *(const bf16x8*)(bufA + aOff + 16384 + mi * 2048 + koff[ks]);

        // ---- q10: af-hi x bfLo ----
        __builtin_amdgcn_s_setprio(1);
        #pragma unroll
        for (int mi = 0; mi < 4; ++mi)
            #pragma unroll
            for (int ni = 0; ni < 2; ++ni)
                #pragma unroll
                for (int ks = 0; ks < 2; ++ks)
                    acc[4 + mi][ni] = __builtin_amdgcn_mfma_f32_16x16x32_bf16(
                        af[mi][ks], bfLo[ni][ks], acc[4 + mi][ni], 0, 0, 0);
        __builtin_amdgcn_s_setprio(0);

        // ---- q11: af-hi x bfHi ----
        __builtin_amdgcn_s_setprio(1);
        #pragma unroll
        for (int mi = 0; mi < 4; ++mi)
            #pragma unroll
            for (int ni = 0; ni < 2; ++ni)
                #pragma unroll
                for (int ks = 0; ks < 2; ++ks)
                    acc[4 + mi][2 + ni] = __builtin_amdgcn_mfma_f32_16x16x32_bf16(
                        af[mi][ks], bfHi[ni][ks], acc[4 + mi][2 + ni], 0, 0, 0);
        __builtin_amdgcn_s_setprio(0);

        SCH0();
        if constexpr (MODE == 0) {
            VMC0();          // tile u+1 resident (issued a full tile ago)
            SBAR(); SCH0();  // all waves done reading buf(u); safe to overwrite next
        }
    };

    for (u = 0; u < NTILE - 1; ++u) tile(ModeT<0>{});
    tile(ModeT<1>{});

    // epilogue: write BF16 partials (interleaved-quadrant mapping)
    unsigned short* Pp = P + (size_t)sk * rows * OUT_F;
    const size_t orow0 = (size_t)bm * 256 + (size_t)wr * 64;
    const int    ocol0 = bn * 256 + wc * 32;
    #pragma unroll
    for (int n = 0; n < 4; ++n) {
        const int col = ocol0 + (n & 1) * 16 + (n >> 1) * 128 + fr;
        #pragma unroll
        for (int m = 0; m < 8; ++m) {
            const size_t r0 = orow0 + (m & 3) * 16 + (m >> 2) * 128 + kg * 4;
            #pragma unroll
            for (int j2 = 0; j2 < 4; ++j2)
                Pp[(r0 + j2) * OUT_F + col] = (unsigned short)f2bf(acc[m][n][j2]);
        }
    }
}

// out = P0 + P1 + bias   (bf16 partials, f32 out; 8 elems/thread)
__global__ __launch_bounds__(256)
void reduce_kan(const unsigned short* __restrict__ P,
                const float* __restrict__ bias,
                float* __restrict__ out, int n8, int skStride8)
{
    const ushortx8* p0 = (const ushortx8*)P;
    const ushortx8* p1 = p0 + skStride8;
    const float4* bv = (const float4*)bias;
    float4* o = (float4*)out;
    for (int i = blockIdx.x * blockDim.x + threadIdx.x; i < n8;
         i += gridDim.x * blockDim.x) {
        ushortx8 a = p0[i], b = p1[i];
        float4 c0 = bv[(i & 127) * 2], c1 = bv[(i & 127) * 2 + 1];
        float4 r0, r1;
        r0.x = bf2f(a[0]) + bf2f(b[0]) + c0.x;
        r0.y = bf2f(a[1]) + bf2f(b[1]) + c0.y;
        r0.z = bf2f(a[2]) + bf2f(b[2]) + c0.z;
        r0.w = bf2f(a[3]) + bf2f(b[3]) + c0.w;
        r1.x = bf2f(a[4]) + bf2f(b[4]) + c1.x;
        r1.y = bf2f(a[5]) + bf2f(b[5]) + c1.y;
        r1.z = bf2f(a[6]) + bf2f(b[6]) + c1.z;
        r1.w = bf2f(a[7]) + bf2f(b[7]) + c1.w;
        o[i * 2]     = r0;
        o[i * 2 + 1] = r1;
    }
}

extern "C" void kernel_launch(void* const* d_in, const int* in_sizes, int n_in,
                              void* d_out, int out_size, void* d_ws, size_t ws_size,
                              hipStream_t stream)
{
    const float* x    = (const float*)d_in[0];
    const float* W    = (const float*)d_in[1];
    const float* bias = (const float*)d_in[2];
    const float* spl  = (const float*)d_in[3];
    const float* grid = (const float*)d_in[4];
    float* out = (float*)d_out;

    unsigned short* Bw = (unsigned short*)d_ws;               // 18.9 MB
    unsigned short* Aw = Bw + (size_t)OUT_F * KTOT;

    // per-row ws: A bf16 (18432 B) + 2x bf16 partial (4096 B) = 22528 B
    const size_t bBytes = (size_t)OUT_F * KTOT * 2;
    size_t avail = ws_size > bBytes ? ws_size - bBytes : 0;
    long maxRows = (long)(avail / 22528);
    int chunk = (maxRows >= TOKENS) ? TOKENS : (int)((maxRows / 256) * 256);
    if (chunk < 256) chunk = 256;
    unsigned short* Pp = Aw + (size_t)chunk * KTOT;

    if (chunk == TOKENS) {
        // fused prep (A + B in one BW-bound sweep), then one GEMM + reduce
        prep_fused<<<(TOKENS * IN_F) / 256 + (OUT_F * (KTOT / 8)) / 256,
                     256, 0, stream>>>(x, grid, W, spl, Aw, Bw);
        gemm_kan2<<<(TOKENS >> 8) * 8, 512, 0, stream>>>(Aw, Bw, Pp, TOKENS);
        int n8 = TOKENS * 128;
        reduce_kan<<<2048, 256, 0, stream>>>(Pp, bias, out, n8, n8);
    } else {
        prep_b_kernel<<<(OUT_F * (KTOT / 8)) / 256, 256, 0, stream>>>(W, spl, Bw);
        for (int t0 = 0; t0 < TOKENS; t0 += chunk) {
            int rows = (TOKENS - t0 < chunk) ? (TOKENS - t0) : chunk;
            prep_a_kernel<<<(rows * IN_F) / 256, 256, 0, stream>>>(
                x + (size_t)t0 * IN_F, grid, Aw);
            gemm_kan2<<<(rows >> 8) * 8, 512, 0, stream>>>(Aw, Bw, Pp, rows);
            int n8 = rows * 128;
            int rblocks = (n8 + 255) / 256; if (rblocks > 2048) rblocks = 2048;
            reduce_kan<<<rblocks, 256, 0, stream>>>(
                Pp, bias, out + (size_t)t0 * OUT_F, n8, n8);
        }
    }
}